// Round 6
// baseline (288.759 us; speedup 1.0000x reference)
//
#include <hip/hip_runtime.h>

#define B_    4
#define N_    20000
#define M_    20000
#define K_    16
#define CIN   64
#define CMID  16
#define COUT  67            // CIN + 3 additional channels
#define PPB   4             // 4 waves per block, 1 point per wave per iteration
#define LSTR  17            // padded LDS transpose stride (f32)
#define NXCD  8
#define GRID_BLOCKS 1792    // 224 blocks per XCD
#define WPX   896           // waves per XCD = 224 * 4
#define PTSX  10000         // points per XCD = 80000 / 8

typedef float float4_ __attribute__((ext_vector_type(4)));

__global__ __launch_bounds__(256, 6) void pconv_kernel(
    const float* __restrict__ in_feats,   // [B, N, 64]
    const int*   __restrict__ inds,       // [B, M, 16]
    const float* __restrict__ wn,         // [B, M, 16, 16]
    const float* __restrict__ addl,       // [B, M, 16, 3]
    float*       __restrict__ out)        // [B, M, 1072]
{
    __shared__ float lds_out [PPB][1140];        // padded transpose buf (needs 1138 f32)
    __shared__ float lds_wn  [PPB][K_ * CMID];   // 1 KB per wave
    __shared__ float lds_addl[PPB][52];          // 48 + pad

    const int tid  = threadIdx.x;
    const int lane = tid & 63;
    const int wav  = __builtin_amdgcn_readfirstlane(tid >> 6);

    // XCD-partitioned persistent mapping: blockIdx%8 -> XCD (round-robin dispatch)
    const int xcd = __builtin_amdgcn_readfirstlane(blockIdx.x & (NXCD - 1));
    const int ww  = __builtin_amdgcn_readfirstlane((blockIdx.x >> 3) * PPB + wav); // 0..895
    const int pbase = xcd * PTSX;

    // batch is loop-invariant per XCD: bp in [xcd*10000, xcd*10000+10000)
    const float* bfeat = in_feats + (long)(xcd >> 1) * N_ * CIN;

    // pipeline registers
    float   fC[K_], fN[K_];
    float4_ wC, wN;
    float   aC = 0.f, aN = 0.f;
    int     idxN[K_];                  // uniform -> SGPRs

    int p = ww;                        // local point id within XCD slice
    if (p >= PTSX) return;             // (never with 896 < 10000)

    // ---- prologue: point p fully issued ----
    {
        const int bp = pbase + p;
        const int* pi = inds + bp * K_;
        int idx0[K_];
        #pragma unroll
        for (int k = 0; k < K_; ++k) idx0[k] = pi[k];
        #pragma unroll
        for (int k = 0; k < K_; ++k)
            fC[k] = bfeat[(long)idx0[k] * CIN + lane];
        wC = ((const float4_*)(wn + (long)bp * (K_ * CMID)))[lane];
        if (lane < 48) aC = addl[(long)bp * 48 + lane];
        // idx for p + WPX (one stage ahead of its gathers)
        if (p + WPX < PTSX) {
            const int* pi2 = inds + (bp + WPX) * K_;
            #pragma unroll
            for (int k = 0; k < K_; ++k) idxN[k] = pi2[k];
        }
    }

    while (true) {
        const int  bp   = pbase + p;
        const int  pn   = p + WPX;
        const bool hasN = pn < PTSX;

        // ---- issue NEXT point's vector loads (idxN already resident) ----
        if (hasN) {
            const int bpn = pbase + pn;
            #pragma unroll
            for (int k = 0; k < K_; ++k)
                fN[k] = bfeat[(long)idxN[k] * CIN + lane];    // 16 x 256B coalesced
            wN = ((const float4_*)(wn + (long)bpn * (K_ * CMID)))[lane];
            if (lane < 48) aN = addl[(long)bpn * 48 + lane];
            // idx prefetch two stages ahead
            if (pn + WPX < PTSX) {
                const int* pi2 = inds + (bpn + WPX) * K_;
                #pragma unroll
                for (int k = 0; k < K_; ++k) idxN[k] = pi2[k];
            }
        }

        // ---- stage current wn/addl to LDS (wave-private, no barrier) ----
        *(float4_*)(&lds_wn[wav][lane * 4]) = wC;
        if (lane < 48) lds_addl[wav][lane] = aC;

        // ---- FMA: lane owns channel c = lane; wn via uniform b128 broadcast ----
        float acc[CMID];
        #pragma unroll
        for (int w = 0; w < CMID; ++w) acc[w] = 0.f;

        #pragma unroll
        for (int k = 0; k < K_; ++k) {
            const float* lw = &lds_wn[wav][k * CMID];
            float4_ w0 = *(const float4_*)(lw + 0);
            float4_ w1 = *(const float4_*)(lw + 4);
            float4_ w2 = *(const float4_*)(lw + 8);
            float4_ w3 = *(const float4_*)(lw + 12);
            #pragma unroll
            for (int e = 0; e < 4; ++e) {
                acc[0  + e] += fC[k] * w0[e];
                acc[4  + e] += fC[k] * w1[e];
                acc[8  + e] += fC[k] * w2[e];
                acc[12 + e] += fC[k] * w3[e];
            }
        }

        // ---- padded-LDS transpose ----
        float* lo = &lds_out[wav][0];
        #pragma unroll
        for (int w = 0; w < CMID; ++w)
            lo[lane * LSTR + w] = acc[w];

        // tail channels c = 64+t
        const int t  = lane >> 4;
        const int wt = lane & 15;
        if (lane < 48) {
            float acc2 = 0.f;
            #pragma unroll
            for (int k = 0; k < K_; ++k)
                acc2 += lds_addl[wav][k * 3 + t] * lds_wn[wav][k * CMID + wt];
            lo[(CIN + t) * LSTR + wt] = acc2;
        }

        // ---- contiguous stores: 4 x 1KB + 192B ----
        float* pout = out + (long)bp * (COUT * CMID);
        const int q = lane >> 2;
        const int r = lane & 3;
        #pragma unroll
        for (int pp = 0; pp < 4; ++pp) {
            const float* src = lo + (pp * 16 + q) * LSTR + 4 * r;
            float4_ v = { src[0], src[1], src[2], src[3] };
            *(float4_*)(pout + pp * 256 + lane * 4) = v;
        }
        if (lane < 12) {
            const float* src = lo + (CIN + q) * LSTR + 4 * r;
            float4_ v = { src[0], src[1], src[2], src[3] };
            *(float4_*)(pout + 1024 + lane * 4) = v;
        }

        if (!hasN) break;
        p = pn;
        #pragma unroll
        for (int k = 0; k < K_; ++k) fC[k] = fN[k];
        wC = wN;
        aC = aN;
    }
}

extern "C" void kernel_launch(void* const* d_in, const int* in_sizes, int n_in,
                              void* d_out, int out_size, void* d_ws, size_t ws_size,
                              hipStream_t stream) {
    const float* in_feats = (const float*)d_in[0];
    const int*   ninds    = (const int*)d_in[1];
    const float* wn       = (const float*)d_in[2];
    const float* addl     = (const float*)d_in[3];
    float*       out      = (float*)d_out;

    dim3 grid(GRID_BLOCKS);
    dim3 block(256);
    pconv_kernel<<<grid, block, 0, stream>>>(in_feats, ninds, wn, addl, out);
}

// Round 7
// 136.720 us; speedup vs baseline: 2.1121x; 2.1121x over previous
//
#include <hip/hip_runtime.h>

#define B_    4
#define N_    20000
#define M_    20000
#define K_    16
#define CIN   64
#define CMID  16
#define COUT  67            // CIN + 3 additional channels
#define LSTR  17            // padded LDS transpose stride (f32)
#define NXCD  8
#define PPW   2             // points per wave (straight-line pipelined)
#define PPB   8             // points per block = 4 waves * 2

typedef float float4_ __attribute__((ext_vector_type(4)));

__global__ __launch_bounds__(256, 4) void pconv_kernel(
    const float* __restrict__ in_feats,   // [B, N, 64]
    const int*   __restrict__ inds,       // [B, M, 16]
    const float* __restrict__ wn,         // [B, M, 16, 16]
    const float* __restrict__ addl,       // [B, M, 16, 3]
    float*       __restrict__ out)        // [B, M, 1072]
{
    __shared__ float lds_out[4][(COUT + 1) * LSTR];   // 4 x 4624 B transpose buf
    __shared__ float lds_wn [4][K_ * CMID];           // 4 x 1 KB

    const int tid  = threadIdx.x;
    const int lane = tid & 63;
    const int wav  = tid >> 6;

    // bijective XCD swizzle: 10000 blocks -> 1250 contiguous per XCD slot
    const int qx  = gridDim.x / NXCD;                  // 1250
    const int swz = (blockIdx.x % NXCD) * qx + blockIdx.x / NXCD;

    const int bp0 = __builtin_amdgcn_readfirstlane(swz * PPB + wav * PPW);
    const int b   = bp0 / M_;                          // uniform (slices don't straddle batches)
    const float* bfeat = in_feats + (long)b * N_ * CIN;

    // ---- indices for BOTH points -> SGPRs ----
    const int* piA = inds + (long)bp0 * K_;
    int idxA[K_], idxB[K_];
    #pragma unroll
    for (int k = 0; k < K_; ++k) idxA[k] = piA[k];
    #pragma unroll
    for (int k = 0; k < K_; ++k) idxB[k] = piA[K_ + k];

    // ---- issue ALL vector loads for both points up-front (max MLP) ----
    float fA[K_], fB[K_];
    #pragma unroll
    for (int k = 0; k < K_; ++k)
        fA[k] = bfeat[(long)idxA[k] * CIN + lane];     // 16 x 256B coalesced
    #pragma unroll
    for (int k = 0; k < K_; ++k)
        fB[k] = bfeat[(long)idxB[k] * CIN + lane];     // 16 x 256B coalesced

    const float* pwnA = wn + (long)bp0 * (K_ * CMID);
    float4_ wA = ((const float4_*)pwnA)[lane];                 // 1KB coalesced
    float4_ wB = ((const float4_*)(pwnA + K_ * CMID))[lane];   // 1KB coalesced

    const int t  = lane >> 4;          // tail channel select (lanes 0..47)
    const int wt = lane & 15;
    const int q  = lane >> 2;          // store readback coords
    const int r  = lane & 3;

#define PROCESS(FX, WX, BPX)                                                  \
    {                                                                         \
        *(float4_*)(&lds_wn[wav][lane * 4]) = (WX);                           \
        float acc[CMID];                                                      \
        _Pragma("unroll")                                                     \
        for (int w = 0; w < CMID; ++w) acc[w] = 0.f;                          \
        _Pragma("unroll")                                                     \
        for (int k = 0; k < K_; ++k) {                                        \
            const float* lw = &lds_wn[wav][k * CMID];                         \
            float4_ w0 = *(const float4_*)(lw + 0);                           \
            float4_ w1 = *(const float4_*)(lw + 4);                           \
            float4_ w2 = *(const float4_*)(lw + 8);                           \
            float4_ w3 = *(const float4_*)(lw + 12);                          \
            _Pragma("unroll")                                                 \
            for (int e = 0; e < 4; ++e) {                                     \
                acc[0  + e] += (FX)[k] * w0[e];                               \
                acc[4  + e] += (FX)[k] * w1[e];                               \
                acc[8  + e] += (FX)[k] * w2[e];                               \
                acc[12 + e] += (FX)[k] * w3[e];                               \
            }                                                                 \
        }                                                                     \
        float* lo = &lds_out[wav][0];                                         \
        _Pragma("unroll")                                                     \
        for (int w = 0; w < CMID; ++w)                                        \
            lo[lane * LSTR + w] = acc[w];                                     \
        if (lane < 48) {                                                      \
            const float* padd = addl + (long)(BPX) * (K_ * 3);                \
            float acc2 = 0.f;                                                 \
            _Pragma("unroll")                                                 \
            for (int k = 0; k < K_; ++k) {                                    \
                float a0 = padd[k * 3 + 0];   /* uniform s_loads */           \
                float a1 = padd[k * 3 + 1];                                   \
                float a2 = padd[k * 3 + 2];                                   \
                float av = (t == 0) ? a0 : (t == 1) ? a1 : a2;                \
                acc2 += av * lds_wn[wav][k * CMID + wt];                      \
            }                                                                 \
            lo[(CIN + t) * LSTR + wt] = acc2;                                 \
        }                                                                     \
        float* pout = out + (long)(BPX) * (COUT * CMID);                      \
        _Pragma("unroll")                                                     \
        for (int pp = 0; pp < 4; ++pp) {                                      \
            const float* src = lo + (pp * 16 + q) * LSTR + 4 * r;             \
            float4_ v = { src[0], src[1], src[2], src[3] };                   \
            *(float4_*)(pout + pp * 256 + lane * 4) = v;                      \
        }                                                                     \
        if (lane < 12) {                                                      \
            const float* src = lo + (CIN + q) * LSTR + 4 * r;                 \
            float4_ v = { src[0], src[1], src[2], src[3] };                   \
            *(float4_*)(pout + 1024 + lane * 4) = v;                          \
        }                                                                     \
    }

    PROCESS(fA, wA, bp0)        // B's 17 loads still in flight during this
    PROCESS(fB, wB, bp0 + 1)

#undef PROCESS
}

extern "C" void kernel_launch(void* const* d_in, const int* in_sizes, int n_in,
                              void* d_out, int out_size, void* d_ws, size_t ws_size,
                              hipStream_t stream) {
    const float* in_feats = (const float*)d_in[0];
    const int*   ninds    = (const int*)d_in[1];
    const float* wn       = (const float*)d_in[2];
    const float* addl     = (const float*)d_in[3];
    float*       out      = (float*)d_out;

    const int total_points = B_ * M_;            // 80000
    dim3 grid(total_points / PPB);               // 10000 blocks, 2 points/wave
    dim3 block(256);
    pconv_kernel<<<grid, block, 0, stream>>>(in_feats, ninds, wn, addl, out);
}